// Round 10
// baseline (405.984 us; speedup 1.0000x reference)
//
#include <hip/hip_runtime.h>

// ConvLSTM2D via MFMA implicit-GEMM. B=8,T=16,H=W=64,Cin=32,F=64,3x3 SAME.
// Round 17: synthesis of R15 (best, 365us) and R16 (B-in-regs, 383us).
// R16's regression decomposed: (a) zbuf epilogue exchange (+~1.5us/step),
// (b) A-reads doubled (2pxgrp x 8ngrp -> 16 waves x 4 A-frags = 64KB/iter).
// Fix both while keeping B-in-regs + 16 waves: waves = 4 pxgrp x 4 ngrp,
// wave tile 32px x 64ch (ALL 4 GATES: nt {ngrp,+4,+8,+12} -> gates of
// channel ngrp*16+m colocated in-lane -> R15's shuffle-free epilogue).
// A-reads: 2 frags/wave-iter x 16 waves = 32KB/CU-iter (R15 level).
// B: global->VGPR 1-deep dbuf, no ring -> LDS/iter 32KB (~376cy), B via
// L1 broadcast (4 pxgrp waves read the same 1KB line; 16KB unique from
// L2-resident per-XCD wpk slice). LDS 40.3KB; barrier-free K-loop except
// one hs-publish barrier at s=8. 4 waves/SIMD.
// Keeps: async h-issue (R14), cpre prefetch s=17 (R14), XCD b=bid&7 (R15).
// Pipe model/CU-iter: MFMA 621 | A-LDS 376 | B-L1 ~512 -> ~700-900cy/iter
// with 4-wave TLP vs R15's ~1300.

#define TSTEPS 16

typedef short bf16x8 __attribute__((ext_vector_type(8)));
typedef float f32x4 __attribute__((ext_vector_type(4)));

__device__ __forceinline__ float hsig(float x) {
    return fminf(fmaxf((x + 3.0f) * (1.0f / 6.0f), 0.0f), 1.0f);
}

__device__ __forceinline__ unsigned short f2bf(float f) {
    union { float f; unsigned int u; } v; v.f = f;
    unsigned int r = v.u + 0x7fffu + ((v.u >> 16) & 1u);  // RNE
    return (unsigned short)(r >> 16);
}

// ---- weight prepack: Wg(3,3,32,256), Ug(3,3,64,256) fp32 -> bf16 B-frags ----
// layout out[s(27)][nt(16)][lane(64)][8]: per (s,nt) one contiguous 1 KB line.
__global__ __launch_bounds__(256)
void prepack_w(const float* __restrict__ Wg, const float* __restrict__ Ug,
               unsigned short* __restrict__ out)
{
    int idx = blockIdx.x * 256 + threadIdx.x;   // 27*16*64 = 27648
    if (idx >= 27648) return;
    int lane = idx & 63;
    int nt   = (idx >> 6) & 15;
    int s    = idx >> 10;
    int col = lane & 15, quad = lane >> 4;
    int n = nt * 16 + col;
    int k0 = quad * 8;
    const float* src;
    if (s < 9) {
        src = Wg + ((size_t)s * 32 + k0) * 256 + n;
    } else {
        int ss = s - 9; int tap = ss >> 1; int half = ss & 1;
        src = Ug + ((size_t)tap * 64 + half * 32 + k0) * 256 + n;
    }
    unsigned short tmp[8];
    #pragma unroll
    for (int j = 0; j < 8; ++j) tmp[j] = f2bf(src[(size_t)j * 256]);
    *(uint4*)(out + (size_t)idx * 8) = *(uint4*)tmp;
}

// ---- one ConvLSTM step (NS = 9 for t==0, 27 otherwise) ----
template<int NS>
__global__ __launch_bounds__(1024)
__attribute__((amdgpu_waves_per_eu(4, 4)))
void convlstm_step(const float* __restrict__ x,       // (B,T,64,64,32) fp32
                   const unsigned short* __restrict__ wpk,
                   const float* __restrict__ bias,    // (256)
                   const unsigned short* __restrict__ h_in, // bf16 (B,64,64,64)
                   float* __restrict__ c_st,          // fp32 (B,64,64,64) = d_out
                   unsigned short* __restrict__ h_out,// bf16 ping
                   int t, int is_last)
{
    constexpr bool HP = (NS == 27);

    // tile: 16 rows (y) x 8 cols (x) = 128 px; halo 18x10 = 180 px
    __shared__ __align__(16) unsigned short xs_s[180 * 40];           // 14.4 KB
    __shared__ __align__(16) unsigned short hs_s[HP ? 180 * 72 : 8];  // 25.9 KB

    const int tid  = threadIdx.x;
    // XCD-aware decode: batch = bid&7 -> one batch's 32 tiles on one XCD.
    const int bid  = blockIdx.x;
    const int b    = bid & 7;
    const int tile = bid >> 3;             // 0..31
    const int gx0  = (tile & 7) * 8;
    const int gy0  = (tile >> 3) * 16;

    const int lane  = tid & 63;
    const int w     = tid >> 6;        // wave 0..15
    const int pxgrp = w >> 2;          // 0..3: rows [4*pxgrp, 4*pxgrp+4)
    const int ngrp  = w & 3;           // nt {ngrp, ngrp+4, ngrp+8, ngrp+12}
    const int quad  = lane >> 4;
    const int m     = lane & 15;
    const int ch    = ngrp * 16 + m;   // output channel 0..63 (all 4 gates)

    // ---- h halo: ISSUE loads into regs early (hide under x-stage).
    // 1440 items / 1024 thr = 2 rounds (2nd partial: tid < 416).
    uint4 hv0 = make_uint4(0u,0u,0u,0u), hv1 = make_uint4(0u,0u,0u,0u);
    int ho0 = 0, ho1 = -1;
    if constexpr (HP) {
        const unsigned short* hb = h_in + ((size_t)b * (64 * 64 * 64));
        auto issueH = [&](int idx, uint4& v, int& off) {
            int pix = idx >> 3, q = idx & 7;
            int iy = pix / 10, ix = pix - iy * 10;
            int gy = gy0 + iy - 1, gx = gx0 + ix - 1;
            if ((unsigned)gy < 64u && (unsigned)gx < 64u)
                v = *(const uint4*)(hb + ((size_t)(gy * 64 + gx) * 64) + q * 8);
            off = pix * 72 + q * 8;
        };
        issueH(tid, hv0, ho0);
        if (tid < 416) issueH(tid + 1024, hv1, ho1);
    }

    // ---- stage x halo (fp32 -> bf16); h loads in flight meanwhile ----
    {
        const float* xt = x + (((size_t)b * TSTEPS + t) * (size_t)(64 * 64 * 32));
        #pragma unroll 2
        for (int idx = tid; idx < 180 * 8; idx += 1024) {
            int pix = idx >> 3, q = idx & 7;
            int iy = pix / 10, ix = pix - iy * 10;
            int gy = gy0 + iy - 1, gx = gx0 + ix - 1;
            unsigned short o[4] = {0, 0, 0, 0};
            if ((unsigned)gy < 64u && (unsigned)gx < 64u) {
                float4 v = *(const float4*)(xt + ((size_t)(gy * 64 + gx) * 32) + q * 4);
                o[0] = f2bf(v.x); o[1] = f2bf(v.y); o[2] = f2bf(v.z); o[3] = f2bf(v.w);
            }
            *(ushort4*)(xs_s + pix * 40 + q * 4) = *(ushort4*)o;
        }
    }
    __syncthreads();   // xs_s visible (h still in regs)

    // per-thread A maps: p = mt*16 + m within the wave's 32 px
    int xb[2], hb_[2];
    #pragma unroll
    for (int mt = 0; mt < 2; ++mt) {
        int p = mt * 16 + m;
        int row = pxgrp * 4 + (p >> 3);
        int cc  = p & 7;
        xb[mt]  = (row * 10 + cc) * 40 + quad * 8;
        hb_[mt] = (row * 10 + cc) * 72 + quad * 8;
    }

    // acc init = bias (gate g at n = g*64 + ch)
    f32x4 acc[2][4];   // [mt][gate]
    #pragma unroll
    for (int g = 0; g < 4; ++g) {
        float bv = bias[g * 64 + ch];
        f32x4 bi = (f32x4){bv, bv, bv, bv};
        #pragma unroll
        for (int mt = 0; mt < 2; ++mt) acc[mt][g] = bi;
    }

    // cpre: c_prev for the epilogue cells; prefetched at s==17 (HP)
    float cpre[2][4];
    if constexpr (!HP) {
        #pragma unroll
        for (int mt = 0; mt < 2; ++mt)
            #pragma unroll
            for (int r = 0; r < 4; ++r) cpre[mt][r] = 0.0f;
    }

    // ---- B: demand global->VGPR, 1-deep double buffer.
    // nt = ngrp + 4g -> gate g of channels ngrp*16+[0,16). Same 1 KB line
    // read by the 4 pxgrp-waves of this CU -> L1 broadcast.
    auto loadB = [&](int s, bf16x8* dst) {
        #pragma unroll
        for (int g = 0; g < 4; ++g)
            dst[g] = *(const bf16x8*)(wpk + ((size_t)(s * 16 + ngrp + 4 * g) * 64 + lane) * 8);
    };

    bf16x8 bC[4], bN[4];
    loadB(0, bC);

    // ---- K-loop: barrier-free (B wave-private in regs, A-LDS read-only);
    // one barrier publishes hs between s=8 and s=9.
    #pragma unroll
    for (int s = 0; s < NS; ++s) {
        if (s + 1 < NS) loadB(s + 1, bN);

        bf16x8 a[2];
        if (s < 9) {
            int taplin = (s / 3) * 10 + (s % 3);
            #pragma unroll
            for (int mt = 0; mt < 2; ++mt)
                a[mt] = *(const bf16x8*)(xs_s + xb[mt] + taplin * 40);
        } else {
            int ss = s - 9, tap = ss >> 1, half = ss & 1;
            int taplin = (tap / 3) * 10 + (tap % 3);
            #pragma unroll
            for (int mt = 0; mt < 2; ++mt)
                a[mt] = *(const bf16x8*)(hs_s + hb_[mt] + taplin * 72 + half * 32);
        }

        #pragma unroll
        for (int g = 0; g < 4; ++g)
            #pragma unroll
            for (int mt = 0; mt < 2; ++mt)
                acc[mt][g] = __builtin_amdgcn_mfma_f32_16x16x32_bf16(a[mt], bC[g], acc[mt][g], 0, 0, 0);

        #pragma unroll
        for (int i = 0; i < 4; ++i) bC[i] = bN[i];

        if constexpr (HP) {
            // publish hs between the x-phase (s<9) and h-phase (s>=9)
            if (s == 8) {
                *(uint4*)(hs_s + ho0) = hv0;
                if (ho1 >= 0) *(uint4*)(hs_s + ho1) = hv1;
                __syncthreads();
            }
            // prefetch c_prev ~10 iters before the epilogue consumes it
            if (s == 17) {
                #pragma unroll
                for (int mt = 0; mt < 2; ++mt)
                    #pragma unroll
                    for (int r = 0; r < 4; ++r) {
                        int p = mt * 16 + quad * 4 + r;
                        int row = pxgrp * 4 + (p >> 3), col = p & 7;
                        size_t gidx = (((size_t)b * 64 + (gy0 + row)) * 64 + (gx0 + col)) * 64 + ch;
                        cpre[mt][r] = c_st[gidx];
                    }
            }
        }
    }

    // ---- epilogue: gates colocated in-lane; c from registers ----
    // C/D layout: col(channel) = lane&15, row(pixel) = quad*4 + r
    #pragma unroll
    for (int mt = 0; mt < 2; ++mt) {
        #pragma unroll
        for (int r = 0; r < 4; ++r) {
            int p = mt * 16 + quad * 4 + r;
            int row = pxgrp * 4 + (p >> 3), col = p & 7;
            size_t gidx = (((size_t)b * 64 + (gy0 + row)) * 64 + (gx0 + col)) * 64 + ch;
            float zi = acc[mt][0][r];
            float zf = acc[mt][1][r];
            float zc = acc[mt][2][r];
            float zo = acc[mt][3][r];
            float cn = hsig(zf) * cpre[mt][r] + hsig(zi) * fmaxf(zc, 0.0f);
            float hn = hsig(zo) * fmaxf(cn, 0.0f);
            if (is_last) {
                c_st[gidx] = hn;            // d_out gets final h (fp32)
            } else {
                c_st[gidx] = cn;
                h_out[gidx] = f2bf(hn);
            }
        }
    }
}

extern "C" void kernel_launch(void* const* d_in, const int* in_sizes, int n_in,
                              void* d_out, int out_size, void* d_ws, size_t ws_size,
                              hipStream_t stream) {
    const float* x  = (const float*)d_in[0];
    const float* Wg = (const float*)d_in[1];
    const float* Ug = (const float*)d_in[2];
    const float* bs = (const float*)d_in[3];

    // ws layout: [packed weights 442368 B][h0 bf16 4 MB][h1 bf16 4 MB]
    unsigned short* wpk = (unsigned short*)d_ws;
    unsigned short* h0  = (unsigned short*)((char*)d_ws + 27 * 16 * 64 * 8 * 2);
    unsigned short* h1  = h0 + (size_t)8 * 64 * 64 * 64;
    float* cS = (float*)d_out;

    prepack_w<<<108, 256, 0, stream>>>(Wg, Ug, wpk);

    dim3 grid(256);    // 1D; decode: b = bid&7 (XCD), tile = bid>>3
    dim3 block(1024);  // 16 waves = 4 pxgrp x 4 ngrp = 4 waves/SIMD
    for (int t = 0; t < TSTEPS; ++t) {
        const unsigned short* hin = (t == 0) ? h0 : ((t & 1) ? h0 : h1);
        unsigned short* hout = (t & 1) ? h1 : h0;
        if (t == 0) {
            convlstm_step<9><<<grid, block, 0, stream>>>(x, wpk, bs, hin, cS, hout, t, 0);
        } else {
            convlstm_step<27><<<grid, block, 0, stream>>>(x, wpk, bs, hin, cS, hout,
                                                          t, (t == TSTEPS - 1) ? 1 : 0);
        }
    }
}